// Round 4
// baseline (186.367 us; speedup 1.0000x reference)
//
#include <hip/hip_runtime.h>

#define BATCH 16384
#define CTX 10
#define MAXC 24
#define GRID_MAIN (BATCH / 2)        // one wave (2 rows) per 64-thread block

// Half-wave (32 lanes) per batch row, float4 per lane (32*16B = one 512B
// embedding row). Scores reduced via 5-step reduce-scatter (31 shuffles, and
// lane l ends holding score l), loss computed in parallel (one softplus per
// lane), wave-summed, one plain store per block. No LDS, no barriers, no
// global atomics.
__global__ __launch_bounds__(64) void cbow_hs_main(
    const int* __restrict__ ctx_words,   // [B, CTX]
    const int* __restrict__ paths,       // [B, MAXC]
    const int* __restrict__ codes,       // [B, MAXC]
    const int* __restrict__ mask,        // [B, MAXC]
    const float* __restrict__ W_in,      // [VOCAB, 128]
    const float* __restrict__ W_internal,// [VOCAB-1, 128]
    float* __restrict__ partials)        // [GRID_MAIN]
{
    const int lane = threadIdx.x;        // 0..63
    const int half = lane >> 5;          // which row of the wave's pair
    const int l5   = lane & 31;          // lane within half-wave
    const int row  = blockIdx.x * 2 + half;

    const float4* Win4 = (const float4*)W_in;        // 32 float4 per emb row
    const float4* Wn4  = (const float4*)W_internal;

    // ---- context mean: each lane owns 4 dims ----
    float4 acc = make_float4(0.f, 0.f, 0.f, 0.f);
#pragma unroll
    for (int k = 0; k < CTX; ++k) {
        const int w = ctx_words[row * CTX + k];       // broadcast within half
        const float4 e = Win4[(long)w * 32 + l5];     // 512B coalesced / half
        acc.x += e.x; acc.y += e.y; acc.z += e.z; acc.w += e.w;
    }
    const float inv = 1.0f / (float)CTX;
    acc.x *= inv; acc.y *= inv; acc.z *= inv; acc.w *= inv;

    // ---- per-lane partial dots, padded to 32 scores ----
    float v[32];
#pragma unroll
    for (int l = 0; l < 32; ++l) v[l] = 0.f;
#pragma unroll
    for (int l = 0; l < MAXC; ++l) {
        const int p = paths[row * MAXC + l];
        const float4 e = Wn4[(long)p * 32 + l5];
        v[l] = acc.x * e.x + acc.y * e.y + acc.z * e.z + acc.w * e.w;
    }

    // ---- reduce-scatter across the 32-lane half: 31 shuffles total.
    // After step set {16,8,4,2,1}, lane l5 holds score index
    // (l5&16)+(l5&8)+(l5&4)+(l5&2)+(l5&1) == l5, fully reduced. ----
#pragma unroll
    for (int off = 16; off; off >>= 1) {
        const bool hi = (l5 & off) != 0;
#pragma unroll
        for (int k = 0; k < off; ++k) {               // off == live/2
            const float send = hi ? v[k] : v[k + off];
            const float recv = __shfl_xor(send, off, 64);
            const float keep = hi ? v[k + off] : v[k];
            v[k] = keep + recv;
        }
    }
    const float score = v[0];                          // lane l5 -> score l5

    // ---- parallel masked loss: one softplus per lane ----
    float loss = 0.f;
    if (l5 < MAXC) {
        const int c = codes[row * MAXC + l5];          // coalesced per-lane
        const int m = mask[row * MAXC + l5];
        const float z = c ? score : -score;            // sign*score
        const float sp = fmaxf(-z, 0.f) + log1pf(expf(-fabsf(z)));
        loss = m ? sp : 0.f;
    }

    // ---- sum across all 64 lanes (covers both rows), one store ----
#pragma unroll
    for (int off = 32; off; off >>= 1)
        loss += __shfl_xor(loss, off, 64);
    if (lane == 0)
        partials[blockIdx.x] = loss;
}

__global__ __launch_bounds__(256) void cbow_hs_reduce(
    const float* __restrict__ partials, float* __restrict__ out)
{
    const int tid = threadIdx.x;
    float s = 0.f;
#pragma unroll
    for (int i = 0; i < GRID_MAIN / 256; ++i)          // 32 each
        s += partials[tid + i * 256];
#pragma unroll
    for (int off = 32; off; off >>= 1)
        s += __shfl_xor(s, off, 64);
    __shared__ float red[4];
    if ((tid & 63) == 0) red[tid >> 6] = s;
    __syncthreads();
    if (tid == 0)
        out[0] = (red[0] + red[1] + red[2] + red[3]) * (1.0f / (float)BATCH);
}

extern "C" void kernel_launch(void* const* d_in, const int* in_sizes, int n_in,
                              void* d_out, int out_size, void* d_ws, size_t ws_size,
                              hipStream_t stream) {
    const int*   ctx_words  = (const int*)d_in[0];
    const int*   paths      = (const int*)d_in[1];
    const int*   codes      = (const int*)d_in[2];
    const int*   mask       = (const int*)d_in[3];
    const float* W_in       = (const float*)d_in[4];
    const float* W_internal = (const float*)d_in[5];
    float* out      = (float*)d_out;
    float* partials = (float*)d_ws;   // 8192 floats, fully written before read

    cbow_hs_main<<<GRID_MAIN, 64, 0, stream>>>(
        ctx_words, paths, codes, mask, W_in, W_internal, partials);
    cbow_hs_reduce<<<1, 256, 0, stream>>>(partials, out);
}

// Round 6
// 147.913 us; speedup vs baseline: 1.2600x; 1.2600x over previous
//
#include <hip/hip_runtime.h>

#define BATCH 16384
#define CTX 10
#define MAXC 24
#define ROWS_PER_BLOCK 8              // 4 waves * 2 rows per wave
#define GRID_MAIN (BATCH / ROWS_PER_BLOCK)   // 2048 blocks

// R3 structure (known 65us): half-wave (32 lanes) per row, float4 per lane,
// full 5-step x24 butterfly (independent shuffles, pipelines on DS pipe),
// LDS block reduce, no atomics. R5 change: loss is computed IN PARALLEL --
// after the butterfly every lane holds all 24 scores, lane l5 extracts score
// l5 via compile-time select chain and does ONE softplus (was 24 serial,
// redundant across all 64 lanes).
__global__ __launch_bounds__(256) void cbow_hs_main(
    const int* __restrict__ ctx_words,   // [B, CTX]
    const int* __restrict__ paths,       // [B, MAXC]
    const int* __restrict__ codes,       // [B, MAXC]
    const int* __restrict__ mask,        // [B, MAXC]
    const float* __restrict__ W_in,      // [VOCAB, 128]
    const float* __restrict__ W_internal,// [VOCAB-1, 128]
    float* __restrict__ partials)        // [GRID_MAIN]
{
    const int tid  = threadIdx.x;
    const int lane = tid & 63;
    const int half = lane >> 5;          // which row of the wave's pair
    const int l5   = lane & 31;          // lane within half-wave
    const int wave = tid >> 6;           // 0..3
    const int row  = blockIdx.x * ROWS_PER_BLOCK + wave * 2 + half;

    const float4* Win4 = (const float4*)W_in;        // 32 float4 per emb row
    const float4* Wn4  = (const float4*)W_internal;

    // ---- context mean: each lane owns 4 dims ----
    float4 acc = make_float4(0.f, 0.f, 0.f, 0.f);
#pragma unroll
    for (int k = 0; k < CTX; ++k) {
        const int w = ctx_words[row * CTX + k];       // broadcast within half
        const float4 e = Win4[(long)w * 32 + l5];     // 512B coalesced / half
        acc.x += e.x; acc.y += e.y; acc.z += e.z; acc.w += e.w;
    }
    const float inv = 1.0f / (float)CTX;
    acc.x *= inv; acc.y *= inv; acc.z *= inv; acc.w *= inv;

    // ---- per-lane partial dots for all 24 path nodes ----
    float part[MAXC];
#pragma unroll
    for (int l = 0; l < MAXC; ++l) {
        const int p = paths[row * MAXC + l];
        const float4 e = Wn4[(long)p * 32 + l5];
        part[l] = acc.x * e.x + acc.y * e.y + acc.z * e.z + acc.w * e.w;
    }

    // ---- 5-step butterfly within each 32-lane half (offsets stay in-half);
    // independent shuffles per step -> pipelines well. Every lane ends with
    // all 24 complete scores. ----
#pragma unroll
    for (int off = 16; off; off >>= 1) {
#pragma unroll
        for (int l = 0; l < MAXC; ++l)
            part[l] += __shfl_xor(part[l], off, 64);
    }

    // ---- parallel masked loss: lane l5 (<24) handles node l5 ----
    float loss = 0.f;
    if (l5 < MAXC) {
        // compile-time-unrolled extraction (no runtime reg indexing)
        float s = 0.f;
#pragma unroll
        for (int l = 0; l < MAXC; ++l)
            if (l5 == l) s = part[l];
        const int c = codes[row * MAXC + l5];          // coalesced per-lane
        const int m = mask[row * MAXC + l5];
        const float z = c ? s : -s;                    // sign*score
        const float sp = fmaxf(-z, 0.f) + log1pf(expf(-fabsf(z)));
        loss = m ? sp : 0.f;
    }

    // ---- sum loss across the wave (covers both rows), LDS block reduce ----
#pragma unroll
    for (int off = 32; off; off >>= 1)
        loss += __shfl_xor(loss, off, 64);

    __shared__ float red[4];
    if (lane == 0) red[wave] = loss;
    __syncthreads();
    if (tid == 0)
        partials[blockIdx.x] = red[0] + red[1] + red[2] + red[3];
}

__global__ __launch_bounds__(256) void cbow_hs_reduce(
    const float* __restrict__ partials, float* __restrict__ out)
{
    const int tid = threadIdx.x;
    float s = 0.f;
#pragma unroll
    for (int i = 0; i < GRID_MAIN / 256; ++i)          // 8 each
        s += partials[tid + i * 256];
#pragma unroll
    for (int off = 32; off; off >>= 1)
        s += __shfl_xor(s, off, 64);
    __shared__ float red[4];
    if ((tid & 63) == 0) red[tid >> 6] = s;
    __syncthreads();
    if (tid == 0)
        out[0] = (red[0] + red[1] + red[2] + red[3]) * (1.0f / (float)BATCH);
}

extern "C" void kernel_launch(void* const* d_in, const int* in_sizes, int n_in,
                              void* d_out, int out_size, void* d_ws, size_t ws_size,
                              hipStream_t stream) {
    const int*   ctx_words  = (const int*)d_in[0];
    const int*   paths      = (const int*)d_in[1];
    const int*   codes      = (const int*)d_in[2];
    const int*   mask       = (const int*)d_in[3];
    const float* W_in       = (const float*)d_in[4];
    const float* W_internal = (const float*)d_in[5];
    float* out      = (float*)d_out;
    float* partials = (float*)d_ws;   // 2048 floats, fully written before read

    cbow_hs_main<<<GRID_MAIN, 256, 0, stream>>>(
        ctx_words, paths, codes, mask, W_in, W_internal, partials);
    cbow_hs_reduce<<<1, 256, 0, stream>>>(partials, out);
}

// Round 7
// 146.871 us; speedup vs baseline: 1.2689x; 1.0071x over previous
//
#include <hip/hip_runtime.h>

#define BATCH 16384
#define CTX 10
#define MAXC 24
#define ROWS_PER_BLOCK 8              // 4 waves * 2 rows per wave
#define GRID_MAIN (BATCH / ROWS_PER_BLOCK)   // 2048 blocks

// R6 structure (44us) + deep gather pipeline. Half-wave (32 lanes) per row,
// float4 per lane. R7 changes, both targeting VMEM concurrency:
//  (a) indices fetched with ONE coalesced load per table (lane j holds index
//      j of its half) and broadcast via __shfl -> 34 index VMEM instrs become
//      2 VMEM + bpermutes on the idle DS pipe;
//  (b) all 24 path gathers issued into distinct named regs BEFORE the dots,
//      __launch_bounds__(256,2) lifts the VGPR cap so they stay in flight
//      (was VGPR=36 -> ~5 outstanding -> serialized batches).
__global__ __launch_bounds__(256, 2) void cbow_hs_main(
    const int* __restrict__ ctx_words,   // [B, CTX]
    const int* __restrict__ paths,       // [B, MAXC]
    const int* __restrict__ codes,       // [B, MAXC]
    const int* __restrict__ mask,        // [B, MAXC]
    const float* __restrict__ W_in,      // [VOCAB, 128]
    const float* __restrict__ W_internal,// [VOCAB-1, 128]
    float* __restrict__ partials)        // [GRID_MAIN]
{
    const int tid  = threadIdx.x;
    const int lane = tid & 63;
    const int half = lane >> 5;          // which row of the wave's pair
    const int l5   = lane & 31;          // lane within half-wave
    const int wave = tid >> 6;           // 0..3
    const int row  = blockIdx.x * ROWS_PER_BLOCK + wave * 2 + half;
    const int hbase = lane & 32;         // shfl source base for this half

    const float4* Win4 = (const float4*)W_in;        // 32 float4 per emb row
    const float4* Wn4  = (const float4*)W_internal;

    // ---- coalesced index prefetch: lane j (<24 / <10) of each half holds
    // index j for its row; broadcast later via shfl ----
    int pidx = 0, cidx = 0;
    if (l5 < MAXC) pidx = paths[row * MAXC + l5];
    if (l5 < CTX)  cidx = ctx_words[row * CTX + l5];

    // ---- context gathers: all 10 in flight, then accumulate ----
    float4 ce[CTX];
#pragma unroll
    for (int k = 0; k < CTX; ++k) {
        const int w = __shfl(cidx, hbase + k, 64);
        ce[k] = Win4[(long)w * 32 + l5];             // 512B coalesced / half
    }
    float4 acc = make_float4(0.f, 0.f, 0.f, 0.f);
#pragma unroll
    for (int k = 0; k < CTX; ++k) {
        acc.x += ce[k].x; acc.y += ce[k].y; acc.z += ce[k].z; acc.w += ce[k].w;
    }
    const float inv = 1.0f / (float)CTX;
    acc.x *= inv; acc.y *= inv; acc.z *= inv; acc.w *= inv;

    // ---- path gathers: all 24 issued before any dot ----
    float4 pe[MAXC];
#pragma unroll
    for (int l = 0; l < MAXC; ++l) {
        const int p = __shfl(pidx, hbase + l, 64);
        pe[l] = Wn4[(long)p * 32 + l5];
    }
    float part[MAXC];
#pragma unroll
    for (int l = 0; l < MAXC; ++l)
        part[l] = acc.x * pe[l].x + acc.y * pe[l].y
                + acc.z * pe[l].z + acc.w * pe[l].w;

    // ---- 5-step butterfly within each 32-lane half: every lane ends with
    // all 24 complete scores ----
#pragma unroll
    for (int off = 16; off; off >>= 1) {
#pragma unroll
        for (int l = 0; l < MAXC; ++l)
            part[l] += __shfl_xor(part[l], off, 64);
    }

    // ---- parallel masked loss: lane l5 (<24) handles node l5 ----
    float loss = 0.f;
    if (l5 < MAXC) {
        float s = 0.f;
#pragma unroll
        for (int l = 0; l < MAXC; ++l)               // compile-time extract
            if (l5 == l) s = part[l];
        const int c = codes[row * MAXC + l5];        // coalesced per-lane
        const int m = mask[row * MAXC + l5];
        const float z = c ? s : -s;                  // sign*score
        const float sp = fmaxf(-z, 0.f) + log1pf(expf(-fabsf(z)));
        loss = m ? sp : 0.f;
    }

    // ---- sum loss across the wave (covers both rows), LDS block reduce ----
#pragma unroll
    for (int off = 32; off; off >>= 1)
        loss += __shfl_xor(loss, off, 64);

    __shared__ float red[4];
    if (lane == 0) red[wave] = loss;
    __syncthreads();
    if (tid == 0)
        partials[blockIdx.x] = red[0] + red[1] + red[2] + red[3];
}

__global__ __launch_bounds__(256) void cbow_hs_reduce(
    const float* __restrict__ partials, float* __restrict__ out)
{
    const int tid = threadIdx.x;
    float s = 0.f;
#pragma unroll
    for (int i = 0; i < GRID_MAIN / 256; ++i)        // 8 each
        s += partials[tid + i * 256];
#pragma unroll
    for (int off = 32; off; off >>= 1)
        s += __shfl_xor(s, off, 64);
    __shared__ float red[4];
    if ((tid & 63) == 0) red[tid >> 6] = s;
    __syncthreads();
    if (tid == 0)
        out[0] = (red[0] + red[1] + red[2] + red[3]) * (1.0f / (float)BATCH);
}

extern "C" void kernel_launch(void* const* d_in, const int* in_sizes, int n_in,
                              void* d_out, int out_size, void* d_ws, size_t ws_size,
                              hipStream_t stream) {
    const int*   ctx_words  = (const int*)d_in[0];
    const int*   paths      = (const int*)d_in[1];
    const int*   codes      = (const int*)d_in[2];
    const int*   mask       = (const int*)d_in[3];
    const float* W_in       = (const float*)d_in[4];
    const float* W_internal = (const float*)d_in[5];
    float* out      = (float*)d_out;
    float* partials = (float*)d_ws;   // 2048 floats, fully written before read

    cbow_hs_main<<<GRID_MAIN, 256, 0, stream>>>(
        ctx_words, paths, codes, mask, W_in, W_internal, partials);
    cbow_hs_reduce<<<1, 256, 0, stream>>>(partials, out);
}